// Round 5
// baseline (132.465 us; speedup 1.0000x reference)
//
#include <hip/hip_runtime.h>

// Relation Graph Attention (RGAT), MI355X. v5.
// R=3, B=2, N=2048, CIN=256, NH=4, D=64.
//  K0    : W -> Wt bf16 [r][o][k]
//  K0out : out = broadcast(xs @ W_out) across heads   (residual init)
//  K1    : per (r,b,itile64,head): hs-tile = xs @ W[r][:,head] (MFMA);
//          epilogue: eip/ein/ejp/ejn = exp2({1,0.1}*logit*log2e) + V frag-tiled
//  K2    : per (r,b,itile16): 8 waves = 4 heads x 2 j-halves; reg-staged adj ->
//          swizzled LDS (2-deep pipeline, raw s_barrier, no vmcnt drain);
//          P = adj * max(eip*ejp, ein*ejn)   [== adj*exp2(lrelu(ei+ej)), exp2 monotone]
//          P@V MFMA, den via ones-MFMA, block den exchange, cross-q merge, atomicAdd.

constexpr int R_ = 3, B_ = 2, N_ = 2048, CIN_ = 256, NH_ = 4, D_ = 64, NHD_ = 256;
constexpr int IT2_ = 16;               // i rows per K2 block
constexpr int BK2_ = 128;              // j per half-stage per wave
constexpr int NST2_ = 1024 / BK2_;     // 8 superstages
constexpr float LEAKY = 0.1f;
constexpr float LOG2E = 1.4426950408889634f;

typedef float f32x4 __attribute__((ext_vector_type(4)));
typedef __bf16 bf16x8 __attribute__((ext_vector_type(8)));

// workspace layout (bytes)
constexpr size_t OFF_WT  = 0;                                      // ushort [R][NHD][CIN]
constexpr size_t SZ_WT   = (size_t)R_ * NHD_ * CIN_ * 2;
constexpr size_t OFF_VT  = OFF_WT + SZ_WT;                         // ushort, frag-tiled
constexpr size_t SZ_VT   = (size_t)R_ * B_ * NH_ * D_ * N_ * 2;
constexpr size_t SZ_E    = (size_t)R_ * B_ * NH_ * N_ * 4;         // one [R][B][NH][N] f32
constexpr size_t OFF_EIP = OFF_VT + SZ_VT;
constexpr size_t OFF_EIN = OFF_EIP + SZ_E;
constexpr size_t OFF_EJP = OFF_EIN + SZ_E;
constexpr size_t OFF_EJN = OFF_EJP + SZ_E;

__device__ __forceinline__ unsigned short f2bf_bits(float f) {
    __bf16 b = (__bf16)f;
    return __builtin_bit_cast(unsigned short, b);
}

// ---------------- K0: transpose+cast W -> Wt bf16 [r][o][k] ----------------
__global__ void k0_wt(const float* __restrict__ W, unsigned short* __restrict__ Wt) {
    int of = blockIdx.x * 256 + threadIdx.x;       // 0..196607
    int r = of >> 16;
    int rem = of & 65535;
    int o = rem >> 8;
    int k = rem & 255;
    float v = W[((size_t)(r * CIN_ + k)) * NHD_ + o];
    Wt[of] = f2bf_bits(v);
}

// ---------------- K0out: out[b][n][h*64+d] = (xs @ W_out)[b][n][d] ----------------
__global__ __launch_bounds__(256) void k0_out(const float* __restrict__ xs,
                                              const float* __restrict__ Wout,
                                              float* __restrict__ out) {
    int flat_row = blockIdx.x * 4 + (threadIdx.x >> 6);   // 0..4095 = b*N+n
    int d = threadIdx.x & 63;
    const float* xrow = xs + (size_t)flat_row * CIN_;
    float acc = 0.f;
#pragma unroll 8
    for (int k = 0; k < CIN_; ++k)
        acc += xrow[k] * Wout[k * D_ + d];
    float* o = out + (size_t)flat_row * NHD_ + d;
    o[0] = acc; o[64] = acc; o[128] = acc; o[192] = acc;
}

// ---------------- K1: per-head hs GEMM + exp2-logit epilogue + frag-tiled V ----------------
// grid: R*B*32*4 = 768 blocks, 256 threads (4 waves x 16 rows); head = blockIdx&3
__global__ __launch_bounds__(256) void k1_hs(const float* __restrict__ xs,
                                             const unsigned short* __restrict__ Wt,
                                             const float* __restrict__ al,
                                             const float* __restrict__ ar,
                                             unsigned short* __restrict__ Vt,
                                             float* __restrict__ eip,
                                             float* __restrict__ ein,
                                             float* __restrict__ ejp,
                                             float* __restrict__ ejn) {
    __shared__ unsigned short lds2[64][72];

    int x = blockIdx.x;
    int ct = x & 3;                        // head
    int itile = (x >> 2) & 31;
    int b = (x >> 7) & 1;
    int r = x >> 8;
    int tid = threadIdx.x;
    int l = tid & 63;
    int w = tid >> 6;
    int l15 = l & 15;
    int lg = l >> 4;
    int n0 = itile * 64;

    const float* xrow = xs + ((size_t)(b * N_ + n0 + w * 16 + l15)) * CIN_;
    const unsigned short* wt_base = Wt + ((size_t)r * NHD_ + ct * 64) * CIN_;

    f32x4 acc[4] = {};

#pragma unroll
    for (int ks = 0; ks < 8; ++ks) {
        int k8 = ks * 32 + lg * 8;
        float4 x0 = *(const float4*)(xrow + k8);
        float4 x1 = *(const float4*)(xrow + k8 + 4);
        bf16x8 a;
        a[0] = (__bf16)x0.x; a[1] = (__bf16)x0.y; a[2] = (__bf16)x0.z; a[3] = (__bf16)x0.w;
        a[4] = (__bf16)x1.x; a[5] = (__bf16)x1.y; a[6] = (__bf16)x1.z; a[7] = (__bf16)x1.w;
#pragma unroll
        for (int nf = 0; nf < 4; ++nf) {
            bf16x8 bf = *(const bf16x8*)(wt_base + ((size_t)(nf * 16 + l15)) * CIN_ + k8);
            acc[nf] = __builtin_amdgcn_mfma_f32_16x16x32_bf16(a, bf, acc[nf], 0, 0, 0);
        }
    }

    // --- logit epilogue: store exp2-transformed row/col factors ---
    float alv[4], arv[4];
#pragma unroll
    for (int nf = 0; nf < 4; ++nf) {
        alv[nf] = al[r * D_ + nf * 16 + l15];
        arv[nf] = ar[r * D_ + nf * 16 + l15];
    }
#pragma unroll
    for (int reg = 0; reg < 4; ++reg) {
        float pi = 0.f, pj = 0.f;
#pragma unroll
        for (int nf = 0; nf < 4; ++nf) {
            float v = acc[nf][reg];
            pi += v * alv[nf];
            pj += v * arv[nf];
        }
#pragma unroll
        for (int m = 1; m < 16; m <<= 1) {
            pi += __shfl_xor(pi, m, 64);
            pj += __shfl_xor(pj, m, 64);
        }
        if (l15 == 0) {
            int i = n0 + w * 16 + lg * 4 + reg;
            size_t eoff = ((size_t)((r * B_ + b) * NH_ + ct)) * N_ + i;
            float si = pi * LOG2E, sj = pj * LOG2E;
            eip[eoff] = __builtin_amdgcn_exp2f(si);
            ein[eoff] = __builtin_amdgcn_exp2f(LEAKY * si);
            ejp[eoff] = __builtin_amdgcn_exp2f(sj);
            ejn[eoff] = __builtin_amdgcn_exp2f(LEAKY * sj);
        }
    }

    // --- V store in MFMA-B-fragment tile order via LDS transpose ---
#pragma unroll
    for (int nf = 0; nf < 4; ++nf)
#pragma unroll
        for (int reg = 0; reg < 4; ++reg)
            lds2[w * 16 + lg * 4 + reg][nf * 16 + l15] = f2bf_bits(acc[nf][reg]);
    __syncthreads();

    size_t hb = ((size_t)((r * B_ + b) * NH_ + ct)) * (size_t)(D_ * N_) + (size_t)itile * 4096;
#pragma unroll
    for (int it = 0; it < 4; ++it) {
        int f4 = it * 256 + tid;               // 0..1023 (ushort4 index)
        int e4  = f4 & 1;
        int ll  = (f4 >> 1) & 63;
        int nf  = (f4 >> 7) & 3;
        int jtl = f4 >> 9;
        int col = nf * 16 + (ll & 15);
        int rowb = jtl * 32 + ((ll >> 4) * 8) + e4 * 4;
        ushort4 v;
        v.x = lds2[rowb + 0][col];
        v.y = lds2[rowb + 1][col];
        v.z = lds2[rowb + 2][col];
        v.w = lds2[rowb + 3][col];
        *(ushort4*)(Vt + hb + (size_t)f4 * 4) = v;
    }
}

// ---------------- K2: masked attention via factored-exp, P@V, normalize ----------------
// grid: R*B*(N/16) = 768 blocks of 512 threads (8 waves: h = w&3, q = w>>2)
__global__ __launch_bounds__(512, 6) void k2_attn(const float* __restrict__ adjs,
                                                  const unsigned short* __restrict__ vt2,
                                                  const float* __restrict__ eip,
                                                  const float* __restrict__ ein,
                                                  const float* __restrict__ ejp,
                                                  const float* __restrict__ ejn,
                                                  float* __restrict__ out) {
    __shared__ __align__(16) float adj_lds[2][IT2_ * 256];   // 2 x 16 KB, XOR-swizzled
    __shared__ float den_sh[2][NH_][IT2_];

    int x = blockIdx.x;
    x = (x & 7) * 96 + (x >> 3);           // XCD-chunked swizzle (768 = 8*96, bijective)
    int itile = x & 127;
    int b = (x >> 7) & 1;
    int r = x >> 8;
    int tid = threadIdx.x;
    int l = tid & 63;
    int w = tid >> 6;
    int h = w & 3;                         // head
    int qh = w >> 2;                       // j-half
    int l15 = l & 15;
    int lg = l >> 4;
    int rx = l15 & 7;
    int i0 = itile * IT2_;

    const float* adj_base = adjs + ((size_t)(r * B_ + b)) * N_ * N_ + (size_t)i0 * N_;
    size_t rowoff = ((size_t)((r * B_ + b) * NH_ + h)) * N_;
    const float* ejpb = ejp + rowoff + qh * 1024;
    const float* ejnb = ejn + rowoff + qh * 1024;
    float eipv = eip[rowoff + i0 + l15];
    float einv = ein[rowoff + i0 + l15];
    const unsigned short* vtb = vt2 + ((size_t)((r * B_ + b) * NH_ + h)) * (size_t)(D_ * N_);

    // staging geometry: 512 threads x 2 float4 cover 16 rows x 256 cols
    int cg = tid & 63;                     // granule within row (0..63)
    int r0 = tid >> 6;                     // row (0..7); second load row+8
    int half = cg >> 5, c32 = cg & 31;
    const float* gs0 = adj_base + (size_t)r0 * N_ + half * 1024 + c32 * 4;
    const float* gs1 = gs0 + 8 * N_;
    int wo0 = r0 * 256 + ((cg ^ (r0 & 7)) << 2);
    int wo1 = (r0 + 8) * 256 + ((cg ^ (r0 & 7)) << 2);

    float* bufE = &adj_lds[0][0];
    float* bufO = &adj_lds[1][0];

    // ones B-frag (col 0) for den-via-MFMA
    bf16x8 onesb;
    {
        __bf16 o1 = (l15 == 0) ? (__bf16)1.0f : (__bf16)0.0f;
#pragma unroll
        for (int e = 0; e < 8; ++e) onesb[e] = o1;
    }

    f32x4 acc[4] = {};
    f32x4 accD = {};

    auto compute = [&](const float* __restrict__ buf, int s) {
        const float* rp = buf + l15 * 256;
#pragma unroll
        for (int sub = 0; sub < 4; ++sub) {
            int jl = s * BK2_ + sub * 32 + lg * 8;          // within this wave's half
            float4 p0 = *(const float4*)(ejpb + jl);
            float4 p1 = *(const float4*)(ejpb + jl + 4);
            float4 n0 = *(const float4*)(ejnb + jl);
            float4 n1 = *(const float4*)(ejnb + jl + 4);
            int gb = qh * 32 + sub * 8 + 2 * lg;
            float4 a0 = *(const float4*)(rp + ((gb ^ rx) << 2));
            float4 a1 = *(const float4*)(rp + (((gb + 1) ^ rx) << 2));
            float pv[8] = {p0.x, p0.y, p0.z, p0.w, p1.x, p1.y, p1.z, p1.w};
            float nv[8] = {n0.x, n0.y, n0.z, n0.w, n1.x, n1.y, n1.z, n1.w};
            float av[8] = {a0.x, a0.y, a0.z, a0.w, a1.x, a1.y, a1.z, a1.w};
            bf16x8 af;
#pragma unroll
            for (int e = 0; e < 8; ++e) {
                // adj * exp2(lrelu(ei+ej)) == adj * max(eip*ejp, ein*ejn)
                float p = av[e] * fmaxf(eipv * pv[e], einv * nv[e]);
                af[e] = (__bf16)p;
            }
            accD = __builtin_amdgcn_mfma_f32_16x16x32_bf16(af, onesb, accD, 0, 0, 0);
            int jt = qh * 32 + s * 4 + sub;
#pragma unroll
            for (int nf = 0; nf < 4; ++nf) {
                bf16x8 bf = *(const bf16x8*)(vtb + ((size_t)(jt * 4 + nf) * 64 + l) * 8);
                acc[nf] = __builtin_amdgcn_mfma_f32_16x16x32_bf16(af, bf, acc[nf], 0, 0, 0);
            }
        }
    };

    // prologue: load stages 0,1; stage 0 -> bufE
    float4 rA0 = *(const float4*)(gs0);
    float4 rA1 = *(const float4*)(gs1);
    float4 rB0 = *(const float4*)(gs0 + BK2_);
    float4 rB1 = *(const float4*)(gs1 + BK2_);
    *(float4*)(bufE + wo0) = rA0;
    *(float4*)(bufE + wo1) = rA1;
    asm volatile("s_waitcnt lgkmcnt(0)" ::: "memory");
    __builtin_amdgcn_s_barrier();

    for (int s2 = 0; s2 < NST2_ / 2; ++s2) {
        int s = s2 * 2;
        if (s + 2 < NST2_) {
            rA0 = *(const float4*)(gs0 + (s + 2) * BK2_);
            rA1 = *(const float4*)(gs1 + (s + 2) * BK2_);
        }
        compute(bufE, s);
        *(float4*)(bufO + wo0) = rB0;
        *(float4*)(bufO + wo1) = rB1;
        asm volatile("s_waitcnt lgkmcnt(0)" ::: "memory");
        __builtin_amdgcn_s_barrier();
        if (s + 3 < NST2_) {
            rB0 = *(const float4*)(gs0 + (s + 3) * BK2_);
            rB1 = *(const float4*)(gs1 + (s + 3) * BK2_);
        }
        compute(bufO, s + 1);
        if (s + 2 < NST2_) {
            *(float4*)(bufE + wo0) = rA0;
            *(float4*)(bufE + wo1) = rA1;
        }
        asm volatile("s_waitcnt lgkmcnt(0)" ::: "memory");
        __builtin_amdgcn_s_barrier();
    }

    // --- block-level denominator: accD col 0 lives in lanes l15==0 ---
    if (l15 == 0) {
#pragma unroll
        for (int reg = 0; reg < 4; ++reg)
            den_sh[qh][h][lg * 4 + reg] = accD[reg];
    }
    __syncthreads();
    float inv[4];
#pragma unroll
    for (int reg = 0; reg < 4; ++reg) {
        float dd = den_sh[0][h][lg * 4 + reg] + den_sh[1][h][lg * 4 + reg];
        inv[reg] = dd > 0.f ? 1.0f / dd : 0.f;
    }

    // --- cross-q merge in LDS (reuse adj_lds), then one atomicAdd per elem ---
    float* accsh = &adj_lds[0][0];         // [4 heads][16 rows][64 cols] = 16 KB
    if (qh == 1) {
#pragma unroll
        for (int nf = 0; nf < 4; ++nf)
#pragma unroll
            for (int reg = 0; reg < 4; ++reg)
                accsh[(h * 16 + lg * 4 + reg) * 64 + nf * 16 + l15] = acc[nf][reg] * inv[reg];
    }
    __syncthreads();
    if (qh == 0) {
        float* ob = out + ((size_t)(b * N_ + i0)) * NHD_ + h * 64;
#pragma unroll
        for (int nf = 0; nf < 4; ++nf)
#pragma unroll
            for (int reg = 0; reg < 4; ++reg) {
                float v = acc[nf][reg] * inv[reg]
                        + accsh[(h * 16 + lg * 4 + reg) * 64 + nf * 16 + l15];
                atomicAdd(ob + (size_t)(lg * 4 + reg) * NHD_ + nf * 16 + l15, v);
            }
    }
}

extern "C" void kernel_launch(void* const* d_in, const int* in_sizes, int n_in,
                              void* d_out, int out_size, void* d_ws, size_t ws_size,
                              hipStream_t stream) {
    const float* xs   = (const float*)d_in[0];
    const float* adjs = (const float*)d_in[1];
    const float* W    = (const float*)d_in[2];
    const float* al   = (const float*)d_in[3];
    const float* ar   = (const float*)d_in[4];
    const float* Wout = (const float*)d_in[5];
    float* out = (float*)d_out;

    char* ws = (char*)d_ws;
    unsigned short* Wt = (unsigned short*)(ws + OFF_WT);
    unsigned short* Vt = (unsigned short*)(ws + OFF_VT);
    float* eip = (float*)(ws + OFF_EIP);
    float* ein = (float*)(ws + OFF_EIN);
    float* ejp = (float*)(ws + OFF_EJP);
    float* ejn = (float*)(ws + OFF_EJN);

    k0_wt<<<dim3((R_ * NHD_ * CIN_) / 256), dim3(256), 0, stream>>>(W, Wt);
    k0_out<<<dim3(B_ * N_ / 4), dim3(256), 0, stream>>>(xs, Wout, out);
    k1_hs<<<dim3(R_ * B_ * 32 * 4), dim3(256), 0, stream>>>(xs, Wt, al, ar, Vt, eip, ein, ejp, ejn);
    k2_attn<<<dim3(R_ * B_ * (N_ / IT2_)), dim3(512), 0, stream>>>(adjs, Vt, eip, ein, ejp, ejn, out);
}

// Round 6
// 103.680 us; speedup vs baseline: 1.2776x; 1.2776x over previous
//
#include <hip/hip_runtime.h>

// Relation Graph Attention (RGAT), MI355X. v6.
// R=3, B=2, N=2048, CIN=256, NH=4, D=64.
//  K0 : W -> Wt bf16 [r][o][k]; Wout -> WoT bf16 [o][k]
//  K1 : per (r,b,itile64,head): hs-tile = xs @ W[r][:,head] (MFMA);
//       epilogue: eip/ein f32 + ej2 = packed {bf16 exp2(sj), bf16 exp2(.1 sj)};
//       V frag-tiled store; (r0,h0) blocks also compute xo = xs @ W_out.
//  K2 : per (r,b,itile16): 8 waves = 4 heads x 2 j-halves; reg-staged adj ->
//       swizzled LDS (2-deep pipeline, raw s_barrier, no vmcnt drain);
//       P = adj * max(eip*ejp, ein*ejn)  [== adj*exp2(lrelu(ei+ej))];
//       P@V MFMA, den via ones-MFMA, block den exchange, cross-q merge,
//       normalized DISJOINT store to num[r] (no atomics).
//  K3 : out = xo_broadcast + sum_r num[r]

constexpr int R_ = 3, B_ = 2, N_ = 2048, CIN_ = 256, NH_ = 4, D_ = 64, NHD_ = 256;
constexpr int IT2_ = 16;               // i rows per K2 block
constexpr int BK2_ = 128;              // j per half-stage per wave
constexpr int NST2_ = 1024 / BK2_;     // 8 superstages
constexpr float LEAKY = 0.1f;
constexpr float LOG2E = 1.4426950408889634f;

typedef float f32x4 __attribute__((ext_vector_type(4)));
typedef __bf16 bf16x8 __attribute__((ext_vector_type(8)));

// workspace layout (bytes)
constexpr size_t OFF_WT  = 0;                                      // ushort [R][NHD][CIN]
constexpr size_t SZ_WT   = (size_t)R_ * NHD_ * CIN_ * 2;           // 393216
constexpr size_t OFF_WOT = OFF_WT + SZ_WT;                         // ushort [D][CIN]
constexpr size_t SZ_WOT  = (size_t)D_ * CIN_ * 2;                  // 32768
constexpr size_t OFF_VT  = OFF_WOT + SZ_WOT;                       // ushort, frag-tiled
constexpr size_t SZ_VT   = (size_t)R_ * B_ * NH_ * D_ * N_ * 2;
constexpr size_t SZ_E    = (size_t)R_ * B_ * NH_ * N_ * 4;         // [R][B][NH][N]
constexpr size_t OFF_EIP = OFF_VT + SZ_VT;
constexpr size_t OFF_EIN = OFF_EIP + SZ_E;
constexpr size_t OFF_EJ2 = OFF_EIN + SZ_E;                         // u32 packed bf16 pair
constexpr size_t OFF_XO  = OFF_EJ2 + SZ_E;                         // float [B][N][D]
constexpr size_t SZ_XO   = (size_t)B_ * N_ * D_ * 4;
constexpr size_t OFF_NUM = OFF_XO + SZ_XO;                         // float [R][B][N][NHD]

__device__ __forceinline__ unsigned short f2bf_bits(float f) {
    __bf16 b = (__bf16)f;
    return __builtin_bit_cast(unsigned short, b);
}

// ---------------- K0: transpose+cast W and Wout ----------------
__global__ void k0_wt(const float* __restrict__ W, const float* __restrict__ Wout,
                      unsigned short* __restrict__ Wt, unsigned short* __restrict__ WoT) {
    int of = blockIdx.x * 256 + threadIdx.x;       // 0..212991
    if (of < 196608) {
        int r = of >> 16;
        int rem = of & 65535;
        int o = rem >> 8;
        int k = rem & 255;
        Wt[of] = f2bf_bits(W[((size_t)(r * CIN_ + k)) * NHD_ + o]);
    } else {
        int idx = of - 196608;                     // 0..16383
        int o = idx >> 8, k = idx & 255;
        WoT[idx] = f2bf_bits(Wout[k * D_ + o]);
    }
}

// ---------------- K1: per-head hs GEMM + factored-exp epilogue + frag-tiled V ----------------
// grid: R*B*32*4 = 768 blocks, 256 threads (4 waves x 16 rows); head = blockIdx&3
__global__ __launch_bounds__(256) void k1_hs(const float* __restrict__ xs,
                                             const unsigned short* __restrict__ Wt,
                                             const unsigned short* __restrict__ WoT,
                                             const float* __restrict__ al,
                                             const float* __restrict__ ar,
                                             unsigned short* __restrict__ Vt,
                                             float* __restrict__ eip,
                                             float* __restrict__ ein,
                                             unsigned int* __restrict__ ej2,
                                             float* __restrict__ xo) {
    __shared__ unsigned short lds2[64][72];

    int x = blockIdx.x;
    int ct = x & 3;                        // head
    int itile = (x >> 2) & 31;
    int b = (x >> 7) & 1;
    int r = x >> 8;
    int tid = threadIdx.x;
    int l = tid & 63;
    int w = tid >> 6;
    int l15 = l & 15;
    int lg = l >> 4;
    int n0 = itile * 64;
    bool do_xo = (r == 0) && (ct == 0);

    const float* xrow = xs + ((size_t)(b * N_ + n0 + w * 16 + l15)) * CIN_;
    const unsigned short* wt_base = Wt + ((size_t)r * NHD_ + ct * 64) * CIN_;

    f32x4 acc[4] = {};
    f32x4 acc2[4] = {};

#pragma unroll
    for (int ks = 0; ks < 8; ++ks) {
        int k8 = ks * 32 + lg * 8;
        float4 x0 = *(const float4*)(xrow + k8);
        float4 x1 = *(const float4*)(xrow + k8 + 4);
        bf16x8 a;
        a[0] = (__bf16)x0.x; a[1] = (__bf16)x0.y; a[2] = (__bf16)x0.z; a[3] = (__bf16)x0.w;
        a[4] = (__bf16)x1.x; a[5] = (__bf16)x1.y; a[6] = (__bf16)x1.z; a[7] = (__bf16)x1.w;
#pragma unroll
        for (int nf = 0; nf < 4; ++nf) {
            bf16x8 bf = *(const bf16x8*)(wt_base + ((size_t)(nf * 16 + l15)) * CIN_ + k8);
            acc[nf] = __builtin_amdgcn_mfma_f32_16x16x32_bf16(a, bf, acc[nf], 0, 0, 0);
        }
        if (do_xo) {
#pragma unroll
            for (int nf = 0; nf < 4; ++nf) {
                bf16x8 bf = *(const bf16x8*)(WoT + ((size_t)(nf * 16 + l15)) * CIN_ + k8);
                acc2[nf] = __builtin_amdgcn_mfma_f32_16x16x32_bf16(a, bf, acc2[nf], 0, 0, 0);
            }
        }
    }

    // --- logit epilogue: factored exp2 forms ---
    float alv[4], arv[4];
#pragma unroll
    for (int nf = 0; nf < 4; ++nf) {
        alv[nf] = al[r * D_ + nf * 16 + l15];
        arv[nf] = ar[r * D_ + nf * 16 + l15];
    }
#pragma unroll
    for (int reg = 0; reg < 4; ++reg) {
        float pi = 0.f, pj = 0.f;
#pragma unroll
        for (int nf = 0; nf < 4; ++nf) {
            float v = acc[nf][reg];
            pi += v * alv[nf];
            pj += v * arv[nf];
        }
#pragma unroll
        for (int m = 1; m < 16; m <<= 1) {
            pi += __shfl_xor(pi, m, 64);
            pj += __shfl_xor(pj, m, 64);
        }
        if (l15 == 0) {
            int i = n0 + w * 16 + lg * 4 + reg;
            size_t eoff = ((size_t)((r * B_ + b) * NH_ + ct)) * N_ + i;
            float si = pi * LOG2E, sj = pj * LOG2E;
            eip[eoff] = __builtin_amdgcn_exp2f(si);
            ein[eoff] = __builtin_amdgcn_exp2f(LEAKY * si);
            unsigned lo = f2bf_bits(__builtin_amdgcn_exp2f(sj));
            unsigned hi = f2bf_bits(__builtin_amdgcn_exp2f(LEAKY * sj));
            ej2[eoff] = lo | (hi << 16);
        }
    }

    // --- xo store (r==0, head==0 blocks) ---
    if (do_xo) {
#pragma unroll
        for (int nf = 0; nf < 4; ++nf)
#pragma unroll
            for (int reg = 0; reg < 4; ++reg) {
                int row = n0 + w * 16 + lg * 4 + reg;
                xo[((size_t)(b * N_ + row)) * D_ + nf * 16 + l15] = acc2[nf][reg];
            }
    }

    // --- V store in MFMA-B-fragment tile order via LDS transpose ---
#pragma unroll
    for (int nf = 0; nf < 4; ++nf)
#pragma unroll
        for (int reg = 0; reg < 4; ++reg)
            lds2[w * 16 + lg * 4 + reg][nf * 16 + l15] = f2bf_bits(acc[nf][reg]);
    __syncthreads();

    size_t hb = ((size_t)((r * B_ + b) * NH_ + ct)) * (size_t)(D_ * N_) + (size_t)itile * 4096;
#pragma unroll
    for (int it = 0; it < 4; ++it) {
        int f4 = it * 256 + tid;               // 0..1023 (ushort4 index)
        int e4  = f4 & 1;
        int ll  = (f4 >> 1) & 63;
        int nf  = (f4 >> 7) & 3;
        int jtl = f4 >> 9;
        int col = nf * 16 + (ll & 15);
        int rowb = jtl * 32 + ((ll >> 4) * 8) + e4 * 4;
        ushort4 v;
        v.x = lds2[rowb + 0][col];
        v.y = lds2[rowb + 1][col];
        v.z = lds2[rowb + 2][col];
        v.w = lds2[rowb + 3][col];
        *(ushort4*)(Vt + hb + (size_t)f4 * 4) = v;
    }
}

// ---------------- K2: masked attention via packed factored-exp, P@V ----------------
// grid: R*B*(N/16) = 768 blocks of 512 threads (8 waves: h = w&3, q = w>>2)
__global__ __launch_bounds__(512, 6) void k2_attn(const float* __restrict__ adjs,
                                                  const unsigned short* __restrict__ vt2,
                                                  const float* __restrict__ eip,
                                                  const float* __restrict__ ein,
                                                  const unsigned int* __restrict__ ej2,
                                                  float* __restrict__ num) {
    __shared__ __align__(16) float adj_lds[2][IT2_ * 256];   // 2 x 16 KB, XOR-swizzled
    __shared__ float den_sh[2][NH_][IT2_];

    int x = blockIdx.x;
    x = (x & 7) * 96 + (x >> 3);           // XCD-chunked swizzle (768 = 8*96, bijective)
    int itile = x & 127;
    int b = (x >> 7) & 1;
    int r = x >> 8;
    int tid = threadIdx.x;
    int l = tid & 63;
    int w = tid >> 6;
    int h = w & 3;                         // head
    int qh = w >> 2;                       // j-half
    int l15 = l & 15;
    int lg = l >> 4;
    int rx = l15 & 7;
    int i0 = itile * IT2_;

    const float* adj_base = adjs + ((size_t)(r * B_ + b)) * N_ * N_ + (size_t)i0 * N_;
    size_t rowoff = ((size_t)((r * B_ + b) * NH_ + h)) * N_;
    const unsigned int* ej2b = ej2 + rowoff + qh * 1024;
    float eipv = eip[rowoff + i0 + l15];
    float einv = ein[rowoff + i0 + l15];
    const unsigned short* vtb = vt2 + ((size_t)((r * B_ + b) * NH_ + h)) * (size_t)(D_ * N_);

    // staging geometry: 512 threads x 2 float4 cover 16 rows x 256 cols
    int cg = tid & 63;                     // granule within row (0..63)
    int r0 = tid >> 6;                     // row (0..7); second load row+8
    int half = cg >> 5, c32 = cg & 31;
    const float* gs0 = adj_base + (size_t)r0 * N_ + half * 1024 + c32 * 4;
    const float* gs1 = gs0 + 8 * N_;
    int wo0 = r0 * 256 + ((cg ^ (r0 & 7)) << 2);
    int wo1 = (r0 + 8) * 256 + ((cg ^ (r0 & 7)) << 2);

    float* bufE = &adj_lds[0][0];
    float* bufO = &adj_lds[1][0];

    // ones B-frag (col 0) for den-via-MFMA
    bf16x8 onesb;
    {
        __bf16 o1 = (l15 == 0) ? (__bf16)1.0f : (__bf16)0.0f;
#pragma unroll
        for (int e = 0; e < 8; ++e) onesb[e] = o1;
    }

    f32x4 acc[4] = {};
    f32x4 accD = {};

    auto compute = [&](const float* __restrict__ buf, int s) {
        const float* rp = buf + l15 * 256;
#pragma unroll
        for (int sub = 0; sub < 4; ++sub) {
            int jl = s * BK2_ + sub * 32 + lg * 8;          // within this wave's half
            uint4 u0 = *(const uint4*)(ej2b + jl);
            uint4 u1 = *(const uint4*)(ej2b + jl + 4);
            int gb = qh * 32 + sub * 8 + 2 * lg;
            float4 a0 = *(const float4*)(rp + ((gb ^ rx) << 2));
            float4 a1 = *(const float4*)(rp + (((gb + 1) ^ rx) << 2));
            unsigned uv[8] = {u0.x, u0.y, u0.z, u0.w, u1.x, u1.y, u1.z, u1.w};
            float av[8] = {a0.x, a0.y, a0.z, a0.w, a1.x, a1.y, a1.z, a1.w};
            bf16x8 af;
#pragma unroll
            for (int e = 0; e < 8; ++e) {
                // adj * exp2(lrelu(ei+ej)) == adj * max(eip*ejp, ein*ejn)
                float pj = __builtin_bit_cast(float, uv[e] << 16);
                float nj = __builtin_bit_cast(float, uv[e] & 0xffff0000u);
                float p = av[e] * fmaxf(eipv * pj, einv * nj);
                af[e] = (__bf16)p;
            }
            accD = __builtin_amdgcn_mfma_f32_16x16x32_bf16(af, onesb, accD, 0, 0, 0);
            int jt = qh * 32 + s * 4 + sub;
#pragma unroll
            for (int nf = 0; nf < 4; ++nf) {
                bf16x8 bf = *(const bf16x8*)(vtb + ((size_t)(jt * 4 + nf) * 64 + l) * 8);
                acc[nf] = __builtin_amdgcn_mfma_f32_16x16x32_bf16(af, bf, acc[nf], 0, 0, 0);
            }
        }
    };

    // prologue: load stages 0,1; stage 0 -> bufE
    float4 rA0 = *(const float4*)(gs0);
    float4 rA1 = *(const float4*)(gs1);
    float4 rB0 = *(const float4*)(gs0 + BK2_);
    float4 rB1 = *(const float4*)(gs1 + BK2_);
    *(float4*)(bufE + wo0) = rA0;
    *(float4*)(bufE + wo1) = rA1;
    asm volatile("s_waitcnt lgkmcnt(0)" ::: "memory");
    __builtin_amdgcn_s_barrier();

    for (int s2 = 0; s2 < NST2_ / 2; ++s2) {
        int s = s2 * 2;
        if (s + 2 < NST2_) {
            rA0 = *(const float4*)(gs0 + (s + 2) * BK2_);
            rA1 = *(const float4*)(gs1 + (s + 2) * BK2_);
        }
        compute(bufE, s);
        *(float4*)(bufO + wo0) = rB0;
        *(float4*)(bufO + wo1) = rB1;
        asm volatile("s_waitcnt lgkmcnt(0)" ::: "memory");
        __builtin_amdgcn_s_barrier();
        if (s + 3 < NST2_) {
            rB0 = *(const float4*)(gs0 + (s + 3) * BK2_);
            rB1 = *(const float4*)(gs1 + (s + 3) * BK2_);
        }
        compute(bufO, s + 1);
        if (s + 2 < NST2_) {
            *(float4*)(bufE + wo0) = rA0;
            *(float4*)(bufE + wo1) = rA1;
        }
        asm volatile("s_waitcnt lgkmcnt(0)" ::: "memory");
        __builtin_amdgcn_s_barrier();
    }

    // --- block-level denominator: accD col 0 lives in lanes l15==0 ---
    if (l15 == 0) {
#pragma unroll
        for (int reg = 0; reg < 4; ++reg)
            den_sh[qh][h][lg * 4 + reg] = accD[reg];
    }
    __syncthreads();
    float inv[4];
#pragma unroll
    for (int reg = 0; reg < 4; ++reg) {
        float dd = den_sh[0][h][lg * 4 + reg] + den_sh[1][h][lg * 4 + reg];
        inv[reg] = dd > 0.f ? 1.0f / dd : 0.f;
    }

    // --- cross-q merge in LDS (reuse adj_lds), then disjoint store to num[r] ---
    float* accsh = &adj_lds[0][0];         // [4 heads][16 rows][64 cols] = 16 KB
    if (qh == 1) {
#pragma unroll
        for (int nf = 0; nf < 4; ++nf)
#pragma unroll
            for (int reg = 0; reg < 4; ++reg)
                accsh[(h * 16 + lg * 4 + reg) * 64 + nf * 16 + l15] = acc[nf][reg] * inv[reg];
    }
    __syncthreads();
    if (qh == 0) {
        float* nb = num + ((size_t)((r * B_ + b) * N_ + i0)) * NHD_ + h * 64;
#pragma unroll
        for (int nf = 0; nf < 4; ++nf)
#pragma unroll
            for (int reg = 0; reg < 4; ++reg) {
                float v = acc[nf][reg] * inv[reg]
                        + accsh[(h * 16 + lg * 4 + reg) * 64 + nf * 16 + l15];
                nb[(size_t)(lg * 4 + reg) * NHD_ + nf * 16 + l15] = v;
            }
    }
}

// ---------------- K3: out = xo_broadcast + sum_r num[r] ----------------
__global__ void k3_out(const float* __restrict__ num,
                       const float* __restrict__ xo,
                       float* __restrict__ out) {
    size_t o = (size_t)blockIdx.x * 256 + threadIdx.x;   // < 1048576
    int b = (int)(o >> 19);
    int n = (int)(o >> 8) & 2047;
    int c = (int)(o & 255);
    constexpr size_t RS = (size_t)B_ * N_ * NHD_;
    float v = xo[((size_t)(b * N_ + n)) * D_ + (c & 63)];
    out[o] = v + num[o] + num[o + RS] + num[o + 2 * RS];
}

extern "C" void kernel_launch(void* const* d_in, const int* in_sizes, int n_in,
                              void* d_out, int out_size, void* d_ws, size_t ws_size,
                              hipStream_t stream) {
    const float* xs   = (const float*)d_in[0];
    const float* adjs = (const float*)d_in[1];
    const float* W    = (const float*)d_in[2];
    const float* al   = (const float*)d_in[3];
    const float* ar   = (const float*)d_in[4];
    const float* Wout = (const float*)d_in[5];
    float* out = (float*)d_out;

    char* ws = (char*)d_ws;
    unsigned short* Wt  = (unsigned short*)(ws + OFF_WT);
    unsigned short* WoT = (unsigned short*)(ws + OFF_WOT);
    unsigned short* Vt  = (unsigned short*)(ws + OFF_VT);
    float* eip = (float*)(ws + OFF_EIP);
    float* ein = (float*)(ws + OFF_EIN);
    unsigned int* ej2 = (unsigned int*)(ws + OFF_EJ2);
    float* xo  = (float*)(ws + OFF_XO);
    float* num = (float*)(ws + OFF_NUM);

    k0_wt<<<dim3(832), dim3(256), 0, stream>>>(W, Wout, Wt, WoT);
    k1_hs<<<dim3(R_ * B_ * 32 * 4), dim3(256), 0, stream>>>(xs, Wt, WoT, al, ar, Vt, eip, ein, ej2, xo);
    k2_attn<<<dim3(R_ * B_ * (N_ / IT2_)), dim3(512), 0, stream>>>(adjs, Vt, eip, ein, ej2, num);
    k3_out<<<dim3((B_ * N_ * NHD_) / 256), dim3(256), 0, stream>>>(num, xo, out);
}

// Round 7
// 99.135 us; speedup vs baseline: 1.3362x; 1.0459x over previous
//
#include <hip/hip_runtime.h>

// Relation Graph Attention (RGAT), MI355X. v7.
// R=3, B=2, N=2048, CIN=256, NH=4, D=64.
//  K0 : W -> Wt bf16 [r][o][k]; Wout -> WoT bf16 [o][k]
//  K1 : per (r,b,itile64,head): hs-tile = xs @ W[r][:,head] (MFMA);
//       epilogue: eip/ein f32 + ej2 = packed {bf16 exp2(sj), bf16 exp2(.1 sj)};
//       V frag-tiled store; (r0,h0) blocks also compute xo = xs @ W_out.
//  K2 : per (r,b,itile16): 8 waves = 4 heads x 2 j-halves.
//       adj staged via global_load_lds DMA (pre-swizzled SOURCE, linear LDS dest,
//       swizzled read) -- no ds_write, no lgkm drain, ONE barrier/stage.
//       P = adj * max(eip*ejp, ein*ejn)  [== adj*exp2(lrelu(ei+ej))];
//       P@V MFMA (batched reg loads), den via ones-MFMA, cross-q merge,
//       disjoint store to num[r].
//  K3 : out = xo_broadcast + sum_r num[r]

constexpr int R_ = 3, B_ = 2, N_ = 2048, CIN_ = 256, NH_ = 4, D_ = 64, NHD_ = 256;
constexpr int IT2_ = 16;               // i rows per K2 block
constexpr int BK2_ = 128;              // j per half-stage per wave
constexpr int NST2_ = 1024 / BK2_;     // 8 stages
constexpr float LEAKY = 0.1f;
constexpr float LOG2E = 1.4426950408889634f;

typedef float f32x4 __attribute__((ext_vector_type(4)));
typedef __bf16 bf16x8 __attribute__((ext_vector_type(8)));

// workspace layout (bytes)
constexpr size_t OFF_WT  = 0;                                      // ushort [R][NHD][CIN]
constexpr size_t SZ_WT   = (size_t)R_ * NHD_ * CIN_ * 2;           // 393216
constexpr size_t OFF_WOT = OFF_WT + SZ_WT;                         // ushort [D][CIN]
constexpr size_t SZ_WOT  = (size_t)D_ * CIN_ * 2;                  // 32768
constexpr size_t OFF_VT  = OFF_WOT + SZ_WOT;                       // ushort, frag-tiled
constexpr size_t SZ_VT   = (size_t)R_ * B_ * NH_ * D_ * N_ * 2;
constexpr size_t SZ_E    = (size_t)R_ * B_ * NH_ * N_ * 4;         // [R][B][NH][N]
constexpr size_t OFF_EIP = OFF_VT + SZ_VT;
constexpr size_t OFF_EIN = OFF_EIP + SZ_E;
constexpr size_t OFF_EJ2 = OFF_EIN + SZ_E;                         // u32 packed bf16 pair
constexpr size_t OFF_XO  = OFF_EJ2 + SZ_E;                         // float [B][N][D]
constexpr size_t SZ_XO   = (size_t)B_ * N_ * D_ * 4;
constexpr size_t OFF_NUM = OFF_XO + SZ_XO;                         // float [R][B][N][NHD]

__device__ __forceinline__ unsigned short f2bf_bits(float f) {
    __bf16 b = (__bf16)f;
    return __builtin_bit_cast(unsigned short, b);
}

__device__ __forceinline__ void gld_lds16(const float* g, float* l) {
    __builtin_amdgcn_global_load_lds(
        (const __attribute__((address_space(1))) void*)g,
        (__attribute__((address_space(3))) void*)l, 16, 0, 0);
}

// ---------------- K0: transpose+cast W and Wout ----------------
__global__ void k0_wt(const float* __restrict__ W, const float* __restrict__ Wout,
                      unsigned short* __restrict__ Wt, unsigned short* __restrict__ WoT) {
    int of = blockIdx.x * 256 + threadIdx.x;       // 0..212991
    if (of < 196608) {
        int r = of >> 16;
        int rem = of & 65535;
        int o = rem >> 8;
        int k = rem & 255;
        Wt[of] = f2bf_bits(W[((size_t)(r * CIN_ + k)) * NHD_ + o]);
    } else {
        int idx = of - 196608;                     // 0..16383
        int o = idx >> 8, k = idx & 255;
        WoT[idx] = f2bf_bits(Wout[k * D_ + o]);
    }
}

// ---------------- K1: per-head hs GEMM + factored-exp epilogue + frag-tiled V ----------------
// grid: R*B*32*4 = 768 blocks, 256 threads (4 waves x 16 rows); head = blockIdx&3
__global__ __launch_bounds__(256) void k1_hs(const float* __restrict__ xs,
                                             const unsigned short* __restrict__ Wt,
                                             const unsigned short* __restrict__ WoT,
                                             const float* __restrict__ al,
                                             const float* __restrict__ ar,
                                             unsigned short* __restrict__ Vt,
                                             float* __restrict__ eip,
                                             float* __restrict__ ein,
                                             unsigned int* __restrict__ ej2,
                                             float* __restrict__ xo) {
    __shared__ unsigned short lds2[64][72];

    int x = blockIdx.x;
    int ct = x & 3;                        // head
    int itile = (x >> 2) & 31;
    int b = (x >> 7) & 1;
    int r = x >> 8;
    int tid = threadIdx.x;
    int l = tid & 63;
    int w = tid >> 6;
    int l15 = l & 15;
    int lg = l >> 4;
    int n0 = itile * 64;
    bool do_xo = (r == 0) && (ct == 0);

    const float* xrow = xs + ((size_t)(b * N_ + n0 + w * 16 + l15)) * CIN_;
    const unsigned short* wt_base = Wt + ((size_t)r * NHD_ + ct * 64) * CIN_;

    f32x4 acc[4] = {};
    f32x4 acc2[4] = {};

#pragma unroll
    for (int ks = 0; ks < 8; ++ks) {
        int k8 = ks * 32 + lg * 8;
        float4 x0 = *(const float4*)(xrow + k8);
        float4 x1 = *(const float4*)(xrow + k8 + 4);
        bf16x8 a;
        a[0] = (__bf16)x0.x; a[1] = (__bf16)x0.y; a[2] = (__bf16)x0.z; a[3] = (__bf16)x0.w;
        a[4] = (__bf16)x1.x; a[5] = (__bf16)x1.y; a[6] = (__bf16)x1.z; a[7] = (__bf16)x1.w;
#pragma unroll
        for (int nf = 0; nf < 4; ++nf) {
            bf16x8 bf = *(const bf16x8*)(wt_base + ((size_t)(nf * 16 + l15)) * CIN_ + k8);
            acc[nf] = __builtin_amdgcn_mfma_f32_16x16x32_bf16(a, bf, acc[nf], 0, 0, 0);
        }
        if (do_xo) {
#pragma unroll
            for (int nf = 0; nf < 4; ++nf) {
                bf16x8 bf = *(const bf16x8*)(WoT + ((size_t)(nf * 16 + l15)) * CIN_ + k8);
                acc2[nf] = __builtin_amdgcn_mfma_f32_16x16x32_bf16(a, bf, acc2[nf], 0, 0, 0);
            }
        }
    }

    // --- logit epilogue: factored exp2 forms ---
    float alv[4], arv[4];
#pragma unroll
    for (int nf = 0; nf < 4; ++nf) {
        alv[nf] = al[r * D_ + nf * 16 + l15];
        arv[nf] = ar[r * D_ + nf * 16 + l15];
    }
#pragma unroll
    for (int reg = 0; reg < 4; ++reg) {
        float pi = 0.f, pj = 0.f;
#pragma unroll
        for (int nf = 0; nf < 4; ++nf) {
            float v = acc[nf][reg];
            pi += v * alv[nf];
            pj += v * arv[nf];
        }
#pragma unroll
        for (int m = 1; m < 16; m <<= 1) {
            pi += __shfl_xor(pi, m, 64);
            pj += __shfl_xor(pj, m, 64);
        }
        if (l15 == 0) {
            int i = n0 + w * 16 + lg * 4 + reg;
            size_t eoff = ((size_t)((r * B_ + b) * NH_ + ct)) * N_ + i;
            float si = pi * LOG2E, sj = pj * LOG2E;
            eip[eoff] = __builtin_amdgcn_exp2f(si);
            ein[eoff] = __builtin_amdgcn_exp2f(LEAKY * si);
            unsigned lo = f2bf_bits(__builtin_amdgcn_exp2f(sj));
            unsigned hi = f2bf_bits(__builtin_amdgcn_exp2f(LEAKY * sj));
            ej2[eoff] = lo | (hi << 16);
        }
    }

    // --- xo store (r==0, head==0 blocks) ---
    if (do_xo) {
#pragma unroll
        for (int nf = 0; nf < 4; ++nf)
#pragma unroll
            for (int reg = 0; reg < 4; ++reg) {
                int row = n0 + w * 16 + lg * 4 + reg;
                xo[((size_t)(b * N_ + row)) * D_ + nf * 16 + l15] = acc2[nf][reg];
            }
    }

    // --- V store in MFMA-B-fragment tile order via LDS transpose ---
#pragma unroll
    for (int nf = 0; nf < 4; ++nf)
#pragma unroll
        for (int reg = 0; reg < 4; ++reg)
            lds2[w * 16 + lg * 4 + reg][nf * 16 + l15] = f2bf_bits(acc[nf][reg]);
    __syncthreads();

    size_t hb = ((size_t)((r * B_ + b) * NH_ + ct)) * (size_t)(D_ * N_) + (size_t)itile * 4096;
#pragma unroll
    for (int it = 0; it < 4; ++it) {
        int f4 = it * 256 + tid;               // 0..1023 (ushort4 index)
        int e4  = f4 & 1;
        int ll  = (f4 >> 1) & 63;
        int nf  = (f4 >> 7) & 3;
        int jtl = f4 >> 9;
        int col = nf * 16 + (ll & 15);
        int rowb = jtl * 32 + ((ll >> 4) * 8) + e4 * 4;
        ushort4 v;
        v.x = lds2[rowb + 0][col];
        v.y = lds2[rowb + 1][col];
        v.z = lds2[rowb + 2][col];
        v.w = lds2[rowb + 3][col];
        *(ushort4*)(Vt + hb + (size_t)f4 * 4) = v;
    }
}

// ---------------- K2: masked attention, DMA-staged adj, P@V ----------------
// grid: R*B*(N/16) = 768 blocks of 512 threads (8 waves: h = w&3, q = w>>2)
__global__ __launch_bounds__(512, 6) void k2_attn(const float* __restrict__ adjs,
                                                  const unsigned short* __restrict__ vt2,
                                                  const float* __restrict__ eip,
                                                  const float* __restrict__ ein,
                                                  const unsigned int* __restrict__ ej2,
                                                  float* __restrict__ num) {
    // LDS: 2 x 16 KB adj buffers. Layout: float_off = row*256 + g'*4 + e,
    // where stored granule g' holds global granule g = g' ^ (row&7).
    __shared__ __align__(16) float adj_lds[2][IT2_ * 256];
    __shared__ float den_sh[2][NH_][IT2_];

    int x = blockIdx.x;
    x = (x & 7) * 96 + (x >> 3);           // XCD-chunked swizzle (768 = 8*96, bijective)
    int itile = x & 127;
    int b = (x >> 7) & 1;
    int r = x >> 8;
    int tid = threadIdx.x;
    int l = tid & 63;
    int w = tid >> 6;
    int h = w & 3;                         // head
    int qh = w >> 2;                       // j-half
    int l15 = l & 15;
    int lg = l >> 4;
    int rx = l15 & 7;
    int i0 = itile * IT2_;

    const float* adj_base = adjs + ((size_t)(r * B_ + b)) * N_ * N_ + (size_t)i0 * N_;
    size_t rowoff = ((size_t)((r * B_ + b) * NH_ + h)) * N_;
    const unsigned int* ej2b = ej2 + rowoff + qh * 1024;
    float eipv = eip[rowoff + i0 + l15];
    float einv = ein[rowoff + i0 + l15];
    const unsigned short* vtb = vt2 + ((size_t)((r * B_ + b) * NH_ + h)) * (size_t)(D_ * N_);

    // --- DMA staging geometry ---
    // wave w stages rows w and w+8; lane l covers stored granule g' = l,
    // whose source is global granule g = l ^ (w&7)  ((w+8)&7 == w&7).
    // granule g -> col = (g>>5)*1024 + (g&31)*4  (+ stage*128)
    int g = l ^ (w & 7);
    const float* srcA = adj_base + (size_t)w * N_ + (g >> 5) * 1024 + (g & 31) * 4;
    const float* srcB = srcA + (size_t)8 * N_;
    float* dstA0 = &adj_lds[0][w * 256];           // + lane*16B by HW
    float* dstB0 = &adj_lds[0][2048 + w * 256];
    float* dstA1 = &adj_lds[1][w * 256];
    float* dstB1 = &adj_lds[1][2048 + w * 256];

    // ones B-frag (col 0) for den-via-MFMA
    bf16x8 onesb;
    {
        __bf16 o1 = (l15 == 0) ? (__bf16)1.0f : (__bf16)0.0f;
#pragma unroll
        for (int e = 0; e < 8; ++e) onesb[e] = o1;
    }

    f32x4 acc[4] = {};
    f32x4 accD = {};

    auto compute = [&](const float* __restrict__ buf, int s) {
        const float* rp = buf + l15 * 256;
        // batched loads: all long-latency first, then the VALU/MFMA chain
        bf16x8 vf[4][4];
        uint4 uu[4][2];
        float4 aa[4][2];
#pragma unroll
        for (int sub = 0; sub < 4; ++sub) {
            int jl = s * BK2_ + sub * 32 + lg * 8;          // within this wave's half
            uu[sub][0] = *(const uint4*)(ej2b + jl);
            uu[sub][1] = *(const uint4*)(ej2b + jl + 4);
            int gb = qh * 32 + sub * 8 + 2 * lg;
            aa[sub][0] = *(const float4*)(rp + ((gb ^ rx) << 2));
            aa[sub][1] = *(const float4*)(rp + (((gb + 1) ^ rx) << 2));
            int jt = qh * 32 + s * 4 + sub;
#pragma unroll
            for (int nf = 0; nf < 4; ++nf)
                vf[sub][nf] = *(const bf16x8*)(vtb + ((size_t)(jt * 4 + nf) * 64 + l) * 8);
        }
#pragma unroll
        for (int sub = 0; sub < 4; ++sub) {
            unsigned uv[8] = {uu[sub][0].x, uu[sub][0].y, uu[sub][0].z, uu[sub][0].w,
                              uu[sub][1].x, uu[sub][1].y, uu[sub][1].z, uu[sub][1].w};
            float av[8] = {aa[sub][0].x, aa[sub][0].y, aa[sub][0].z, aa[sub][0].w,
                           aa[sub][1].x, aa[sub][1].y, aa[sub][1].z, aa[sub][1].w};
            bf16x8 af;
#pragma unroll
            for (int e = 0; e < 8; ++e) {
                // adj * exp2(lrelu(ei+ej)) == adj * max(eip*ejp, ein*ejn)
                float pj = __builtin_bit_cast(float, uv[e] << 16);
                float nj = __builtin_bit_cast(float, uv[e] & 0xffff0000u);
                float p = av[e] * fmaxf(eipv * pj, einv * nj);
                af[e] = (__bf16)p;
            }
            accD = __builtin_amdgcn_mfma_f32_16x16x32_bf16(af, onesb, accD, 0, 0, 0);
#pragma unroll
            for (int nf = 0; nf < 4; ++nf)
                acc[nf] = __builtin_amdgcn_mfma_f32_16x16x32_bf16(af, vf[sub][nf], acc[nf], 0, 0, 0);
        }
    };

    // prologue: DMA stage 0 -> buf0
    gld_lds16(srcA, dstA0);
    gld_lds16(srcB, dstB0);
    asm volatile("s_waitcnt vmcnt(0)" ::: "memory");
    __builtin_amdgcn_s_barrier();

#pragma unroll
    for (int i = 0; i < NST2_; ++i) {
        if (i + 1 < NST2_) {               // DMA next stage into the other buffer
            if (i & 1) {
                gld_lds16(srcA + (i + 1) * BK2_, dstA0);
                gld_lds16(srcB + (i + 1) * BK2_, dstB0);
            } else {
                gld_lds16(srcA + (i + 1) * BK2_, dstA1);
                gld_lds16(srcB + (i + 1) * BK2_, dstB1);
            }
        }
        compute(&adj_lds[i & 1][0], i);
        // compute's own load-waits already forced the DMA complete (in-order
        // vmcnt); this explicit wait is ~free and guarantees it.
        asm volatile("s_waitcnt vmcnt(0)" ::: "memory");
        __builtin_amdgcn_s_barrier();
    }

    // --- block-level denominator: accD col 0 lives in lanes l15==0 ---
    if (l15 == 0) {
#pragma unroll
        for (int reg = 0; reg < 4; ++reg)
            den_sh[qh][h][lg * 4 + reg] = accD[reg];
    }
    __syncthreads();
    float inv[4];
#pragma unroll
    for (int reg = 0; reg < 4; ++reg) {
        float dd = den_sh[0][h][lg * 4 + reg] + den_sh[1][h][lg * 4 + reg];
        inv[reg] = dd > 0.f ? 1.0f / dd : 0.f;
    }

    // --- cross-q merge in LDS (reuse adj_lds), then disjoint store to num[r] ---
    float* accsh = &adj_lds[0][0];         // [4 heads][16 rows][64 cols] = 16 KB
    if (qh == 1) {
#pragma unroll
        for (int nf = 0; nf < 4; ++nf)
#pragma unroll
            for (int reg = 0; reg < 4; ++reg)
                accsh[(h * 16 + lg * 4 + reg) * 64 + nf * 16 + l15] = acc[nf][reg] * inv[reg];
    }
    __syncthreads();
    if (qh == 0) {
        float* nb = num + ((size_t)((r * B_ + b) * N_ + i0)) * NHD_ + h * 64;
#pragma unroll
        for (int nf = 0; nf < 4; ++nf)
#pragma unroll
            for (int reg = 0; reg < 4; ++reg) {
                float v = acc[nf][reg] * inv[reg]
                        + accsh[(h * 16 + lg * 4 + reg) * 64 + nf * 16 + l15];
                nb[(size_t)(lg * 4 + reg) * NHD_ + nf * 16 + l15] = v;
            }
    }
}

// ---------------- K3: out = xo_broadcast + sum_r num[r] ----------------
__global__ void k3_out(const float* __restrict__ num,
                       const float* __restrict__ xo,
                       float* __restrict__ out) {
    size_t o = (size_t)blockIdx.x * 256 + threadIdx.x;   // < 1048576
    int b = (int)(o >> 19);
    int n = (int)(o >> 8) & 2047;
    int c = (int)(o & 255);
    constexpr size_t RS = (size_t)B_ * N_ * NHD_;
    float v = xo[((size_t)(b * N_ + n)) * D_ + (c & 63)];
    out[o] = v + num[o] + num[o + RS] + num[o + 2 * RS];
}

extern "C" void kernel_launch(void* const* d_in, const int* in_sizes, int n_in,
                              void* d_out, int out_size, void* d_ws, size_t ws_size,
                              hipStream_t stream) {
    const float* xs   = (const float*)d_in[0];
    const float* adjs = (const float*)d_in[1];
    const float* W    = (const float*)d_in[2];
    const float* al   = (const float*)d_in[3];
    const float* ar   = (const float*)d_in[4];
    const float* Wout = (const float*)d_in[5];
    float* out = (float*)d_out;

    char* ws = (char*)d_ws;
    unsigned short* Wt  = (unsigned short*)(ws + OFF_WT);
    unsigned short* WoT = (unsigned short*)(ws + OFF_WOT);
    unsigned short* Vt  = (unsigned short*)(ws + OFF_VT);
    float* eip = (float*)(ws + OFF_EIP);
    float* ein = (float*)(ws + OFF_EIN);
    unsigned int* ej2 = (unsigned int*)(ws + OFF_EJ2);
    float* xo  = (float*)(ws + OFF_XO);
    float* num = (float*)(ws + OFF_NUM);

    k0_wt<<<dim3(832), dim3(256), 0, stream>>>(W, Wout, Wt, WoT);
    k1_hs<<<dim3(R_ * B_ * 32 * 4), dim3(256), 0, stream>>>(xs, Wt, WoT, al, ar, Vt, eip, ein, ej2, xo);
    k2_attn<<<dim3(R_ * B_ * (N_ / IT2_)), dim3(512), 0, stream>>>(adjs, Vt, eip, ein, ej2, num);
    k3_out<<<dim3((B_ * N_ * NHD_) / 256), dim3(256), 0, stream>>>(num, xo, out);
}